// Round 1
// baseline (115.282 us; speedup 1.0000x reference)
//
#include <hip/hip_runtime.h>
#include <hip/hip_bf16.h>

typedef __attribute__((ext_vector_type(4))) float f32x4;
typedef __attribute__((ext_vector_type(8))) short bf16x8;

constexpr int IN_DIM  = 128;
constexpr int OUT_DIM = 128;
constexpr int BLOCK   = 512;                 // 8 waves
constexpr int WAVES   = 8;
constexpr int CHUNKS  = 4;
constexpr int ROWS_PER_BLOCK = WAVES * 16 * CHUNKS;  // 512
constexpr int VSTRIDE = 136;                 // ushorts per LDS v-row (272 B, padded)

// out[n][o] = sum_k bf16(x[n][k]) * v[o][k] + bq[o]
// v[o][k] = sign(round(sign)) * 2^round(clamp(shift,-14,0))  (exact in bf16)
__global__ __launch_bounds__(BLOCK, 4)
void linshift_kernel(const float* __restrict__ x,
                     const float* __restrict__ shiftp,
                     const float* __restrict__ signp,
                     const float* __restrict__ biasp,
                     float* __restrict__ out)
{
    __shared__ ushort v_lds[OUT_DIM * VSTRIDE];
    __shared__ float  b_lds[OUT_DIM];

    const int t = threadIdx.x;

    // ---- build quantized weight matrix v (bf16 bits) in LDS ----
    // 128x128 elems = 2048 segments of 8; each thread does 4 segments.
    #pragma unroll
    for (int s = 0; s < (OUT_DIM * IN_DIM / 8) / BLOCK; ++s) {
        const int seg = t + s * BLOCK;
        const int row = seg >> 4;          // 16 segments per row
        const int j   = seg & 15;
        const int g   = row * IN_DIM + j * 8;
        f32x4 sh0 = *reinterpret_cast<const f32x4*>(shiftp + g);
        f32x4 sh1 = *reinterpret_cast<const f32x4*>(shiftp + g + 4);
        f32x4 sg0 = *reinterpret_cast<const f32x4*>(signp + g);
        f32x4 sg1 = *reinterpret_cast<const f32x4*>(signp + g + 4);
        union { ushort u[8]; bf16x8 v; } tmp;
        #pragma unroll
        for (int e = 0; e < 8; ++e) {
            float sh = (e < 4) ? sh0[e] : sh1[e - 4];
            float sg = (e < 4) ? sg0[e] : sg1[e - 4];
            sh = fminf(fmaxf(sh, -14.0f), 0.0f);
            const int   si = (int)rintf(sh);          // round-half-even like jnp.round
            const float rs = rintf(sg);               // {-1, 0, 1}
            ushort bits = 0;
            if (rs != 0.0f)
                bits = (ushort)(((rs < 0.0f) ? 0x8000u : 0u) |
                                (unsigned)((127 + si) << 7));   // exact 2^si in bf16
            tmp.u[e] = bits;
        }
        *reinterpret_cast<bf16x8*>(&v_lds[row * VSTRIDE + j * 8]) = tmp.v;
    }
    if (t < OUT_DIM)
        b_lds[t] = floorf(biasp[t] * 65536.0f) * (1.0f / 65536.0f);  // round_to_fixed
    __syncthreads();

    const int wave = t >> 6;
    const int lane = t & 63;
    const int rl = lane & 15;   // x-row within 16-group == D col (m_local)
    const int kb = lane >> 4;   // k-block of 8 within K=32 step

    const long long blockbase = (long long)blockIdx.x * ROWS_PER_BLOCK;

    for (int c = 0; c < CHUNKS; ++c) {
        const long long row = blockbase + (long long)(c * (WAVES * 16) + wave * 16 + rl);
        const float* xp = x + row * IN_DIM + kb * 8;

        // load this lane's B-fragments for all 4 K-steps (8 consecutive f32 each)
        bf16x8 xb[4];
        #pragma unroll
        for (int ks = 0; ks < 4; ++ks) {
            f32x4 f0 = *reinterpret_cast<const f32x4*>(xp + ks * 32);
            f32x4 f1 = *reinterpret_cast<const f32x4*>(xp + ks * 32 + 4);
            union { ushort u[8]; bf16x8 v; } tmp;
            #pragma unroll
            for (int e = 0; e < 4; ++e) {
                __hip_bfloat16 h0 = __float2bfloat16(f0[e]);
                __hip_bfloat16 h1 = __float2bfloat16(f1[e]);
                tmp.u[e]     = *reinterpret_cast<const ushort*>(&h0);
                tmp.u[e + 4] = *reinterpret_cast<const ushort*>(&h1);
            }
            xb[ks] = tmp.v;
        }

        float* op = out + row * OUT_DIM;
        #pragma unroll
        for (int ct = 0; ct < 8; ++ct) {
            f32x4 acc = {0.f, 0.f, 0.f, 0.f};
            #pragma unroll
            for (int ks = 0; ks < 4; ++ks) {
                // A-fragment: v rows ct*16+rl, k = ks*32 + kb*8 .. +8
                bf16x8 vb = *reinterpret_cast<const bf16x8*>(
                    &v_lds[(ct * 16 + rl) * VSTRIDE + ks * 32 + kb * 8]);
                acc = __builtin_amdgcn_mfma_f32_16x16x32_bf16(vb, xb[ks], acc, 0, 0, 0);
            }
            // D[o_local][m_local]: o_local = kb*4 + r, m_local = rl
            // -> this lane's 4 regs are out cols ct*16 + kb*4 + {0..3} of row `row`
            f32x4 bv = *reinterpret_cast<const f32x4*>(&b_lds[ct * 16 + kb * 4]);
            f32x4 o = acc + bv;
            *reinterpret_cast<f32x4*>(op + ct * 16 + kb * 4) = o;
        }
    }
}

extern "C" void kernel_launch(void* const* d_in, const int* in_sizes, int n_in,
                              void* d_out, int out_size, void* d_ws, size_t ws_size,
                              hipStream_t stream) {
    const float* x  = (const float*)d_in[0];
    const float* sh = (const float*)d_in[1];
    const float* sg = (const float*)d_in[2];
    const float* b  = (const float*)d_in[3];
    float* out = (float*)d_out;

    const int N = in_sizes[0] / IN_DIM;          // 524288
    const int grid = N / ROWS_PER_BLOCK;         // 1024 (exact)
    linshift_kernel<<<grid, BLOCK, 0, stream>>>(x, sh, sg, b, out);
}

// Round 2
// 114.877 us; speedup vs baseline: 1.0035x; 1.0035x over previous
//
#include <hip/hip_runtime.h>
#include <hip/hip_bf16.h>

typedef __attribute__((ext_vector_type(4))) float f32x4;
typedef __attribute__((ext_vector_type(8))) short bf16x8;

constexpr int IN_DIM  = 128;
constexpr int OUT_DIM = 128;
constexpr int BLOCK   = 512;                 // 8 waves
constexpr int WAVES   = 8;
constexpr int CHUNKS  = 4;
constexpr int CHUNK_ROWS = WAVES * 16;       // 128 rows per chunk
constexpr int ROWS_PER_BLOCK = CHUNK_ROWS * CHUNKS;  // 512
constexpr int VSTRIDE = 136;                 // ushorts per LDS v-row (272 B, padded)

// out[n][o] = sum_k bf16(x[n][k]) * v[o][k] + bq[o]
// v[o][k] = sign(round(sign)) * 2^round(clamp(shift,-14,0))  (exact in bf16)
__global__ __launch_bounds__(BLOCK, 4)
void linshift_kernel(const float* __restrict__ x,
                     const float* __restrict__ shiftp,
                     const float* __restrict__ signp,
                     const float* __restrict__ biasp,
                     float* __restrict__ out)
{
    __shared__ ushort v_lds[OUT_DIM * VSTRIDE];
    __shared__ float  b_lds[OUT_DIM];

    const int t = threadIdx.x;

    // ---- build quantized weight matrix v (bf16 bits) in LDS ----
    #pragma unroll
    for (int s = 0; s < (OUT_DIM * IN_DIM / 8) / BLOCK; ++s) {
        const int seg = t + s * BLOCK;
        const int row = seg >> 4;          // 16 segments per row
        const int j   = seg & 15;
        const int g   = row * IN_DIM + j * 8;
        f32x4 sh0 = *reinterpret_cast<const f32x4*>(shiftp + g);
        f32x4 sh1 = *reinterpret_cast<const f32x4*>(shiftp + g + 4);
        f32x4 sg0 = *reinterpret_cast<const f32x4*>(signp + g);
        f32x4 sg1 = *reinterpret_cast<const f32x4*>(signp + g + 4);
        union { ushort u[8]; bf16x8 v; } tmp;
        #pragma unroll
        for (int e = 0; e < 8; ++e) {
            float sh = (e < 4) ? sh0[e] : sh1[e - 4];
            float sg = (e < 4) ? sg0[e] : sg1[e - 4];
            sh = fminf(fmaxf(sh, -14.0f), 0.0f);
            const int   si = (int)rintf(sh);          // round-half-even like jnp.round
            const float rs = rintf(sg);               // {-1, 0, 1}
            ushort bits = 0;
            if (rs != 0.0f)
                bits = (ushort)(((rs < 0.0f) ? 0x8000u : 0u) |
                                (unsigned)((127 + si) << 7));   // exact 2^si in bf16
            tmp.u[e] = bits;
        }
        *reinterpret_cast<bf16x8*>(&v_lds[row * VSTRIDE + j * 8]) = tmp.v;
    }
    if (t < OUT_DIM)
        b_lds[t] = floorf(biasp[t] * 65536.0f) * (1.0f / 65536.0f);  // round_to_fixed
    __syncthreads();

    const int wave = t >> 6;
    const int lane = t & 63;
    const int rl = lane & 15;   // x-row within 16-group == D col (m_local)
    const int kb = lane >> 4;   // k-block of 8 within K=32 step

    const long long row0 = (long long)blockIdx.x * ROWS_PER_BLOCK + wave * 16 + rl;
    const float* xp = x + row0 * IN_DIM + kb * 8;
    float* op0 = out + row0 * OUT_DIM;

    // prologue: issue chunk-0 loads
    f32x4 f[8];
    #pragma unroll
    for (int ks = 0; ks < 4; ++ks) {
        f[2 * ks]     = *reinterpret_cast<const f32x4*>(xp + ks * 32);
        f[2 * ks + 1] = *reinterpret_cast<const f32x4*>(xp + ks * 32 + 4);
    }

    #pragma unroll
    for (int c = 0; c < CHUNKS; ++c) {
        // issue next chunk's loads BEFORE consuming this chunk (reg double-buffer)
        f32x4 fn[8];
        if (c + 1 < CHUNKS) {
            const float* xq = xp + (long long)(c + 1) * CHUNK_ROWS * IN_DIM;
            #pragma unroll
            for (int ks = 0; ks < 4; ++ks) {
                fn[2 * ks]     = *reinterpret_cast<const f32x4*>(xq + ks * 32);
                fn[2 * ks + 1] = *reinterpret_cast<const f32x4*>(xq + ks * 32 + 4);
            }
        }

        // convert current chunk f32 -> bf16 fragments (this is where vmcnt waits)
        bf16x8 xb[4];
        #pragma unroll
        for (int ks = 0; ks < 4; ++ks) {
            union { ushort u[8]; bf16x8 v; } tmp;
            #pragma unroll
            for (int e = 0; e < 4; ++e) {
                __hip_bfloat16 h0 = __float2bfloat16(f[2 * ks][e]);
                __hip_bfloat16 h1 = __float2bfloat16(f[2 * ks + 1][e]);
                tmp.u[e]     = *reinterpret_cast<const ushort*>(&h0);
                tmp.u[e + 4] = *reinterpret_cast<const ushort*>(&h1);
            }
            xb[ks] = tmp.v;
        }

        float* op = op0 + (long long)c * CHUNK_ROWS * OUT_DIM;
        #pragma unroll
        for (int ct = 0; ct < 8; ++ct) {
            f32x4 acc = {0.f, 0.f, 0.f, 0.f};
            #pragma unroll
            for (int ks = 0; ks < 4; ++ks) {
                bf16x8 vb = *reinterpret_cast<const bf16x8*>(
                    &v_lds[(ct * 16 + rl) * VSTRIDE + ks * 32 + kb * 8]);
                acc = __builtin_amdgcn_mfma_f32_16x16x32_bf16(vb, xb[ks], acc, 0, 0, 0);
            }
            // lane's 4 regs = out cols ct*16 + kb*4 + {0..3} of row `row0 + c*128`
            f32x4 bv = *reinterpret_cast<const f32x4*>(&b_lds[ct * 16 + kb * 4]);
            f32x4 o = acc + bv;
            __builtin_nontemporal_store(o, reinterpret_cast<f32x4*>(op + ct * 16 + kb * 4));
        }

        #pragma unroll
        for (int i = 0; i < 8; ++i) f[i] = fn[i];
    }
}

extern "C" void kernel_launch(void* const* d_in, const int* in_sizes, int n_in,
                              void* d_out, int out_size, void* d_ws, size_t ws_size,
                              hipStream_t stream) {
    const float* x  = (const float*)d_in[0];
    const float* sh = (const float*)d_in[1];
    const float* sg = (const float*)d_in[2];
    const float* b  = (const float*)d_in[3];
    float* out = (float*)d_out;

    const int N = in_sizes[0] / IN_DIM;          // 524288
    const int grid = N / ROWS_PER_BLOCK;         // 1024 (exact)
    linshift_kernel<<<grid, BLOCK, 0, stream>>>(x, sh, sg, b, out);
}